// Round 3
// baseline (165.231 us; speedup 1.0000x reference)
//
#include <hip/hip_runtime.h>
#include <hip/hip_bf16.h>
#include <stdint.h>

// CAM: out = gamma * (A @ softmax(A^T A)) + x,  A = x.reshape(B, N, C)
// B=32, N=4096 (64*64), C=256.
// Pipeline (K0 removed round 3 — K1 reads x f32 directly, reg-transposes):
//   K1: aTa partials (split-K=4) via bf16 MFMA      (partials in d_out[64MB..96MB))
//   K2: reduce + softmax + transpose -> attnT bf16  (attnT in d_ws, 4MB)
//   K3: out = gamma * (A @ attn) + x                (writes all of d_out)

typedef __attribute__((ext_vector_type(8))) short bf16x8s;
typedef __attribute__((ext_vector_type(8))) unsigned short u16x8;
typedef __attribute__((ext_vector_type(4))) float f32x4;
typedef __attribute__((ext_vector_type(4))) float fl4;
typedef __attribute__((ext_vector_type(4))) uint32_t u32x4;

__device__ __forceinline__ unsigned short f2bf(float f) {
  union { float f; uint32_t u; } v; v.f = f;
  uint32_t r = v.u + 0x7FFFu + ((v.u >> 16) & 1u);
  return (unsigned short)(r >> 16);
}

// packed f32 pair -> 2x bf16 in one u32 (low = lo), RNE via header intrinsic
__device__ __forceinline__ uint32_t cvtpk(float lo, float hi) {
  __hip_bfloat162 h = __float22bfloat162_rn(float2{lo, hi});
  union { __hip_bfloat162 h; uint32_t u; } v; v.h = h; return v.u;
}

__device__ __forceinline__ void gload16(const void* g, void* l) {
  __builtin_amdgcn_global_load_lds(
      (const __attribute__((address_space(1))) uint32_t*)g,
      (__attribute__((address_space(3))) uint32_t*)l, 16, 0, 0);
}

// ---------------------------------------------------------------- K1
// aTa[c,d] = sum_n x[n,c]*x[n,d].  Per WG: 128x128 output quadrant,
// K-chunk of 1024 (split-K=4).  grid = 32*4*4 = 512, 256 threads (4 waves).
// Staging: waves 0-1 stage A-tile, waves 2-3 stage B-tile.  Each thread
// reg-transposes an 8x8 f32 block of x and ds_writes bf16 rows into
// XOR-swizzled LDS ([128 c][64 n], byte ^= (row&7)<<4) — same layout the
// MFMA fragment reads use.  Diagonal tiles (ci==cj) stage A only.
__global__ __launch_bounds__(256, 2) void k1_ata(
    const float* __restrict__ x, float* __restrict__ part) {
  __shared__ __align__(16) unsigned short As[2][128 * 64];
  __shared__ __align__(16) unsigned short Bs[2][128 * 64];

  int bid = blockIdx.x;
  int ks   = bid & 3;
  int tile = (bid >> 2) & 3;
  int b    = bid >> 4;
  int ci = tile >> 1, cj = tile & 1;
  bool diag = (ci == cj);

  const float* xb = x + ((size_t)b << 20);

  int t = threadIdx.x, w = t >> 6, l = t & 63;
  int wm = w >> 1, wn = w & 1;
  int fr = l & 15, fh = l >> 4;

  // staging role
  int g  = w >> 1;            // 0: A operand, 1: B operand
  int u  = t & 127;           // index within operand group
  int cb = (u >> 3) * 8;      // c-block 0..120
  int nb = (u & 7) * 8;       // n-block 0..56
  int cop = g ? cj : ci;
  const float* src = xb + (size_t)cop * 128 + cb;   // + n*256
  unsigned short* dstbase = g ? &Bs[0][0] : &As[0][0];

  f32x4 acc[4][4];
#pragma unroll
  for (int m = 0; m < 4; ++m)
#pragma unroll
    for (int n = 0; n < 4; ++n) acc[m][n] = (f32x4)(0.0f);

  auto STAGE = [&](int bsel, int nofs) {
    if (g == 1 && diag) return;           // B tile == A tile
    const float* s0 = src + (size_t)(nofs + nb) * 256;
    uint32_t ow[8][4];                    // [c-row i][n-word jp]
#pragma unroll
    for (int jp = 0; jp < 4; ++jp) {
      fl4 a0 = *(const fl4*)&s0[(size_t)(2 * jp) * 256];
      fl4 a1 = *(const fl4*)&s0[(size_t)(2 * jp) * 256 + 4];
      fl4 b0 = *(const fl4*)&s0[(size_t)(2 * jp + 1) * 256];
      fl4 b1 = *(const fl4*)&s0[(size_t)(2 * jp + 1) * 256 + 4];
#pragma unroll
      for (int i = 0; i < 4; ++i) {
        ow[i][jp]     = cvtpk(a0[i], b0[i]);
        ow[4 + i][jp] = cvtpk(a1[i], b1[i]);
      }
    }
    unsigned short* ds = dstbase + bsel * (128 * 64);
#pragma unroll
    for (int i = 0; i < 8; ++i) {
      int row = cb + i;
      int byt = row * 128 + ((nb * 2) ^ ((row & 7) << 4));
      *(u32x4*)&ds[byt >> 1] = u32x4{ow[i][0], ow[i][1], ow[i][2], ow[i][3]};
    }
  };

  const int n0base = ks * 1024;
  STAGE(0, n0base);
  __syncthreads();

  int buf = 0;
#pragma unroll 1
  for (int kt = 0; kt < 16; ++kt) {
    if (kt < 15) STAGE(buf ^ 1, n0base + (kt + 1) * 64);
    const unsigned short* Abuf = As[buf];
    const unsigned short* Bbuf = diag ? As[buf] : Bs[buf];
#pragma unroll
    for (int h = 0; h < 2; ++h) {
      bf16x8s afr[4], bfr[4];
#pragma unroll
      for (int m = 0; m < 4; ++m) {
        int row = wm * 64 + m * 16 + fr;
        int byt = row * 128 + ((h * 64 + fh * 16) ^ ((row & 7) << 4));
        afr[m] = *(const bf16x8s*)&Abuf[byt >> 1];
      }
#pragma unroll
      for (int n = 0; n < 4; ++n) {
        int row = wn * 64 + n * 16 + fr;
        int byt = row * 128 + ((h * 64 + fh * 16) ^ ((row & 7) << 4));
        bfr[n] = *(const bf16x8s*)&Bbuf[byt >> 1];
      }
#pragma unroll
      for (int m = 0; m < 4; ++m)
#pragma unroll
        for (int n = 0; n < 4; ++n)
          acc[m][n] = __builtin_amdgcn_mfma_f32_16x16x32_bf16(
              afr[m], bfr[n], acc[m][n], 0, 0, 0);
    }
    __syncthreads();
    buf ^= 1;
  }

  float* pb = part + ((size_t)(b * 4 + ks) << 16);
#pragma unroll
  for (int m = 0; m < 4; ++m) {
    int row = ci * 128 + wm * 64 + m * 16 + fh * 4;
#pragma unroll
    for (int n = 0; n < 4; ++n) {
      int col = cj * 128 + wn * 64 + n * 16 + fr;
#pragma unroll
      for (int i = 0; i < 4; ++i)
        pb[(size_t)(row + i) * 256 + col] = acc[m][n][i];
    }
  }
}

// ---------------------------------------------------------------- K2
// sum 4 split-K partials, softmax over d, write attnT[b][d][c] (bf16).
// grid = 32*4 = 128 blocks (64 c-rows each), 256 threads (4 waves).
__global__ __launch_bounds__(256) void k2_softmax(
    const float* __restrict__ part, unsigned short* __restrict__ attnT) {
  __shared__ unsigned short T[256][66];
  int b = blockIdx.x >> 2, cblk = blockIdx.x & 3;
  int t = threadIdx.x, w = t >> 6, l = t & 63;
  const float* pb = part + ((size_t)b * 4) * 65536 + (size_t)(cblk * 64) * 256;

  for (int it = 0; it < 16; ++it) {
    int c = w * 16 + it;                   // local row 0..63
    float s[4];
#pragma unroll
    for (int i = 0; i < 4; ++i) {
      int d = l + 64 * i;
      float v = 0.0f;
#pragma unroll
      for (int k = 0; k < 4; ++k)
        v += pb[(size_t)k * 65536 + (size_t)c * 256 + d];
      s[i] = v;
    }
    float mx = fmaxf(fmaxf(s[0], s[1]), fmaxf(s[2], s[3]));
    for (int off = 32; off; off >>= 1) mx = fmaxf(mx, __shfl_xor(mx, off));
    float sum = 0.0f;
#pragma unroll
    for (int i = 0; i < 4; ++i) { s[i] = __expf(s[i] - mx); sum += s[i]; }
    for (int off = 32; off; off >>= 1) sum += __shfl_xor(sum, off);
    float inv = 1.0f / sum;
#pragma unroll
    for (int i = 0; i < 4; ++i) T[l + 64 * i][c] = f2bf(s[i] * inv);
  }
  __syncthreads();

  unsigned short* ab = attnT + ((size_t)b << 16) + (size_t)t * 256 + cblk * 64;
#pragma unroll
  for (int c8 = 0; c8 < 8; ++c8) {
    u16x8 v;
#pragma unroll
    for (int j = 0; j < 8; ++j) v[j] = T[t][c8 * 8 + j];
    *(u16x8*)&ab[c8 * 8] = v;
  }
}

// ---------------------------------------------------------------- K3
// out[n,d] = gamma * sum_c x[n,c]*attn[c,d] + x[n,d].
// Per WG: 128n x 256d, K=256 in 8 steps of 32.  grid = 32*32 = 1024.
// A: reg-staged f32->bf16 (packed cvt) into swizzled LDS [128][32].
// B: global_load_lds from attnT into swizzled LDS [256][32].
__global__ __launch_bounds__(256, 2) void k3_av(
    const float* __restrict__ x, const unsigned short* __restrict__ attnT,
    const float* __restrict__ gamma, float* __restrict__ out) {
  __shared__ __align__(16) unsigned short A_s[2][128 * 32];
  __shared__ __align__(16) unsigned short B_s[2][256 * 32];

  int bid = blockIdx.x;
  int b = bid >> 5, mt = bid & 31;
  int n0 = mt << 7;
  const float* xb = x + ((size_t)b << 20);
  const unsigned short* ab = attnT + ((size_t)b << 16);
  float* ob = out + ((size_t)b << 20);

  int t = threadIdx.x, w = t >> 6, l = t & 63;
  int wm = w >> 1, wn = w & 1;
  int fr = l & 15, fh = l >> 4;

  int ar = t >> 1, ah = t & 1;             // A staging: row, half
  const float* aSrc = xb + (size_t)(n0 + ar) * 256 + ah * 16;
  int brow = l >> 2;                       // B staging: row in 16-row segment
  int bhi = (l & 3) ^ (brow & 3);          // pre-swizzled 16B slot

  f32x4 acc[4][8];
#pragma unroll
  for (int m = 0; m < 4; ++m)
#pragma unroll
    for (int n = 0; n < 8; ++n) acc[m][n] = (f32x4)(0.0f);

  auto STAGE_A = [&](int bsel, int k0) {
    uint32_t pk[8];
#pragma unroll
    for (int q = 0; q < 4; ++q) {
      fl4 v = *(const fl4*)&aSrc[k0 + q * 4];
      pk[2 * q]     = cvtpk(v.x, v.y);
      pk[2 * q + 1] = cvtpk(v.z, v.w);
    }
#pragma unroll
    for (int j = 0; j < 2; ++j) {
      int hi = ah * 2 + j;
      int byt = ar * 64 + ((hi ^ (ar & 3)) << 4);
      *(u32x4*)&A_s[bsel][byt >> 1] =
          u32x4{pk[4 * j], pk[4 * j + 1], pk[4 * j + 2], pk[4 * j + 3]};
    }
  };

  auto STAGE_B = [&](int bsel, int k0) {
#pragma unroll
    for (int r = 0; r < 4; ++r) {
      int seg = r * 4 + w;                 // 16 segments of 16 rows
      int row = seg * 16 + brow;
      gload16(&ab[(size_t)row * 256 + k0 + bhi * 8], &B_s[bsel][seg * 512]);
    }
  };

  STAGE_A(0, 0);
  STAGE_B(0, 0);
  __syncthreads();

  int buf = 0;
#pragma unroll 1
  for (int kt = 0; kt < 8; ++kt) {
    if (kt < 7) { STAGE_A(buf ^ 1, (kt + 1) * 32); STAGE_B(buf ^ 1, (kt + 1) * 32); }
    bf16x8s af[4];
#pragma unroll
    for (int m = 0; m < 4; ++m) {
      int row = wm * 64 + m * 16 + fr;
      int byt = row * 64 + ((fh ^ (row & 3)) << 4);
      af[m] = *(const bf16x8s*)&A_s[buf][byt >> 1];
    }
    bf16x8s bf[8];
#pragma unroll
    for (int n = 0; n < 8; ++n) {
      int d = wn * 128 + n * 16 + fr;
      int byt = d * 64 + ((fh ^ (d & 3)) << 4);
      bf[n] = *(const bf16x8s*)&B_s[buf][byt >> 1];
    }
#pragma unroll
    for (int m = 0; m < 4; ++m)
#pragma unroll
      for (int n = 0; n < 8; ++n)
        acc[m][n] = __builtin_amdgcn_mfma_f32_16x16x32_bf16(
            af[m], bf[n], acc[m][n], 0, 0, 0);
    __syncthreads();
    buf ^= 1;
  }

  float g = gamma[0];
#pragma unroll
  for (int m = 0; m < 4; ++m) {
    int row = wm * 64 + m * 16 + fh * 4;
#pragma unroll
    for (int n = 0; n < 8; ++n) {
      int col = wn * 128 + n * 16 + fr;
#pragma unroll
      for (int i = 0; i < 4; ++i) {
        size_t idx = (size_t)(n0 + row + i) * 256 + col;
        ob[idx] = g * acc[m][n][i] + xb[idx];
      }
    }
  }
}

// ---------------------------------------------------------------- launch
extern "C" void kernel_launch(void* const* d_in, const int* in_sizes, int n_in,
                              void* d_out, int out_size, void* d_ws, size_t ws_size,
                              hipStream_t stream) {
  const float* x     = (const float*)d_in[0];
  const float* gamma = (const float*)d_in[1];
  float* out = (float*)d_out;

  // scratch layout: partials (32MB) live in d_out[64MB..96MB) (dead before K3
  // rewrites it); attnT (4MB) in d_ws (K3 reads it while writing d_out).
  float*          part  = (float*)((char*)d_out + (size_t)64 * 1024 * 1024);
  unsigned short* attnT = (unsigned short*)d_ws;

  k1_ata<<<512, 256, 0, stream>>>(x, part);
  k2_softmax<<<128, 256, 0, stream>>>(part, attnT);
  k3_av<<<1024, 256, 0, stream>>>(x, attnT, gamma, out);
}

// Round 4
// 154.961 us; speedup vs baseline: 1.0663x; 1.0663x over previous
//
#include <hip/hip_runtime.h>
#include <hip/hip_bf16.h>
#include <stdint.h>

// CAM: out = gamma * (A @ softmax(A^T A)) + x,  A = x.reshape(B, N, C)
// B=32, N=4096 (64*64), C=256.
// Pipeline:
//   K1: aTa partials (split-K=8) via bf16 MFMA, reads x f32 directly and
//       reg-transposes into swizzled LDS        (partials in d_out[64MB..128MB))
//   K2: reduce + softmax + transpose -> attnT bf16  (attnT in d_ws, 4MB)
//   K3: out = gamma * (A @ attn) + x                (writes all of d_out)
// All three XCD-swizzled: batch b's WGs land on XCD b%8 for L2 locality.

typedef __attribute__((ext_vector_type(8))) short bf16x8s;
typedef __attribute__((ext_vector_type(8))) unsigned short u16x8;
typedef __attribute__((ext_vector_type(4))) float f32x4;
typedef __attribute__((ext_vector_type(4))) float fl4;
typedef __attribute__((ext_vector_type(4))) uint32_t u32x4;

__device__ __forceinline__ unsigned short f2bf(float f) {
  union { float f; uint32_t u; } v; v.f = f;
  uint32_t r = v.u + 0x7FFFu + ((v.u >> 16) & 1u);
  return (unsigned short)(r >> 16);
}

// packed f32 pair -> 2x bf16 in one u32 (low = lo), RNE
__device__ __forceinline__ uint32_t cvtpk(float lo, float hi) {
  __hip_bfloat162 h = __float22bfloat162_rn(float2{lo, hi});
  union { __hip_bfloat162 h; uint32_t u; } v; v.h = h; return v.u;
}

__device__ __forceinline__ void gload16(const void* g, void* l) {
  __builtin_amdgcn_global_load_lds(
      (const __attribute__((address_space(1))) uint32_t*)g,
      (__attribute__((address_space(3))) uint32_t*)l, 16, 0, 0);
}

// ---------------------------------------------------------------- K1
// aTa[c,d] = sum_n x[n,c]*x[n,d].  Per WG: 128x128 output quadrant,
// K-slab of 512 (split-K=8).  grid = 32*4*8 = 1024, 256 threads (4 waves),
// single-buffered 32KB LDS -> 4 WGs/CU for latency hiding.
// Staging: waves 0-1 stage A-tile, waves 2-3 stage B-tile (diag tiles just
// duplicate A into B — balanced, L1-hot).  Each thread reg-transposes an
// 8x8 f32 block of x and writes bf16 c-rows into XOR-swizzled LDS
// ([128 c][64 n], byte ^= (row&7)<<4) matching the MFMA fragment reads.
__global__ __launch_bounds__(256, 4) void k1_ata(
    const float* __restrict__ x, float* __restrict__ part) {
  __shared__ __align__(16) unsigned short As[128 * 64];
  __shared__ __align__(16) unsigned short Bs[128 * 64];

  int d = blockIdx.x;                   // XCD swizzle: xcd = d&7
  int slot = d >> 3;                    // 0..127
  int b    = (d & 7) + 8 * (slot >> 5); // 4 batches per XCD
  int inner = slot & 31;                // 32 WGs per batch
  int ks   = inner & 7;
  int tile = inner >> 3;
  int ci = tile >> 1, cj = tile & 1;

  const float* xb = x + ((size_t)b << 20);

  int t = threadIdx.x, w = t >> 6, l = t & 63;
  int wm = w >> 1, wn = w & 1;
  int fr = l & 15, fh = l >> 4;

  // staging role
  int g  = w >> 1;            // 0: A operand, 1: B operand
  int u  = t & 127;           // index within operand group
  int cb = (u >> 3) * 8;      // c-block 0..120
  int nb = (u & 7) * 8;       // n-block 0..56
  int cop = g ? cj : ci;
  const float* src = xb + (size_t)cop * 128 + cb;   // + n*256
  unsigned short* dst = g ? Bs : As;

  f32x4 acc[4][4];
#pragma unroll
  for (int m = 0; m < 4; ++m)
#pragma unroll
    for (int n = 0; n < 4; ++n) acc[m][n] = (f32x4)(0.0f);

  auto STAGE = [&](int nofs) {
    const float* s0 = src + (size_t)(nofs + nb) * 256;
    uint32_t ow[8][4];                  // [c-row i][n-word jp]
#pragma unroll
    for (int jp = 0; jp < 4; ++jp) {
      fl4 a0 = *(const fl4*)&s0[(size_t)(2 * jp) * 256];
      fl4 a1 = *(const fl4*)&s0[(size_t)(2 * jp) * 256 + 4];
      fl4 b0 = *(const fl4*)&s0[(size_t)(2 * jp + 1) * 256];
      fl4 b1 = *(const fl4*)&s0[(size_t)(2 * jp + 1) * 256 + 4];
#pragma unroll
      for (int i = 0; i < 4; ++i) {
        ow[i][jp]     = cvtpk(a0[i], b0[i]);
        ow[4 + i][jp] = cvtpk(a1[i], b1[i]);
      }
    }
#pragma unroll
    for (int i = 0; i < 8; ++i) {
      int row = cb + i;
      int byt = row * 128 + ((nb * 2) ^ ((row & 7) << 4));
      *(u32x4*)&dst[byt >> 1] = u32x4{ow[i][0], ow[i][1], ow[i][2], ow[i][3]};
    }
  };

  const int n0base = ks * 512;
#pragma unroll 1
  for (int kt = 0; kt < 8; ++kt) {
    STAGE(n0base + kt * 64);
    __syncthreads();
#pragma unroll
    for (int h = 0; h < 2; ++h) {
      bf16x8s afr[4], bfr[4];
#pragma unroll
      for (int m = 0; m < 4; ++m) {
        int row = wm * 64 + m * 16 + fr;
        int byt = row * 128 + ((h * 64 + fh * 16) ^ ((row & 7) << 4));
        afr[m] = *(const bf16x8s*)&As[byt >> 1];
      }
#pragma unroll
      for (int n = 0; n < 4; ++n) {
        int row = wn * 64 + n * 16 + fr;
        int byt = row * 128 + ((h * 64 + fh * 16) ^ ((row & 7) << 4));
        bfr[n] = *(const bf16x8s*)&Bs[byt >> 1];
      }
#pragma unroll
      for (int m = 0; m < 4; ++m)
#pragma unroll
        for (int n = 0; n < 4; ++n)
          acc[m][n] = __builtin_amdgcn_mfma_f32_16x16x32_bf16(
              afr[m], bfr[n], acc[m][n], 0, 0, 0);
    }
    __syncthreads();
  }

  float* pb = part + ((size_t)(b * 8 + ks) << 16);
#pragma unroll
  for (int m = 0; m < 4; ++m) {
    int row = ci * 128 + wm * 64 + m * 16 + fh * 4;
#pragma unroll
    for (int n = 0; n < 4; ++n) {
      int col = cj * 128 + wn * 64 + n * 16 + fr;
#pragma unroll
      for (int i = 0; i < 4; ++i)
        pb[(size_t)(row + i) * 256 + col] = acc[m][n][i];
    }
  }
}

// ---------------------------------------------------------------- K2
// sum 8 split-K partials, softmax over d, write attnT[b][d][c] (bf16).
// grid = 32*4 = 128 blocks (64 c-rows each), 256 threads (4 waves).
__global__ __launch_bounds__(256) void k2_softmax(
    const float* __restrict__ part, unsigned short* __restrict__ attnT) {
  __shared__ unsigned short T[256][66];
  int d = blockIdx.x;
  int b    = (d & 7) + 8 * ((d >> 3) >> 2);   // same XCD as K1's batch b
  int cblk = (d >> 3) & 3;
  int t = threadIdx.x, w = t >> 6, l = t & 63;
  const float* pb = part + ((size_t)b * 8) * 65536 + (size_t)(cblk * 64) * 256;

  for (int it = 0; it < 16; ++it) {
    int c = w * 16 + it;                   // local row 0..63
    float s[4];
#pragma unroll
    for (int i = 0; i < 4; ++i) {
      int dd = l + 64 * i;
      float v = 0.0f;
#pragma unroll
      for (int k = 0; k < 8; ++k)
        v += pb[(size_t)k * 65536 + (size_t)c * 256 + dd];
      s[i] = v;
    }
    float mx = fmaxf(fmaxf(s[0], s[1]), fmaxf(s[2], s[3]));
    for (int off = 32; off; off >>= 1) mx = fmaxf(mx, __shfl_xor(mx, off));
    float sum = 0.0f;
#pragma unroll
    for (int i = 0; i < 4; ++i) { s[i] = __expf(s[i] - mx); sum += s[i]; }
    for (int off = 32; off; off >>= 1) sum += __shfl_xor(sum, off);
    float inv = 1.0f / sum;
#pragma unroll
    for (int i = 0; i < 4; ++i) T[l + 64 * i][c] = f2bf(s[i] * inv);
  }
  __syncthreads();

  unsigned short* ab = attnT + ((size_t)b << 16) + (size_t)t * 256 + cblk * 64;
#pragma unroll
  for (int c8 = 0; c8 < 8; ++c8) {
    u16x8 v;
#pragma unroll
    for (int j = 0; j < 8; ++j) v[j] = T[t][c8 * 8 + j];
    *(u16x8*)&ab[c8 * 8] = v;
  }
}

// ---------------------------------------------------------------- K3
// out[n,d] = gamma * sum_c x[n,c]*attn[c,d] + x[n,d].
// Per WG: 128n x 256d, K=256 in 8 steps of 32.  grid = 32*32 = 1024.
// A: reg-staged f32->bf16 (packed cvt) into swizzled LDS [128][32].
// B: global_load_lds from attnT into swizzled LDS [256][32].
__global__ __launch_bounds__(256, 2) void k3_av(
    const float* __restrict__ x, const unsigned short* __restrict__ attnT,
    const float* __restrict__ gamma, float* __restrict__ out) {
  __shared__ __align__(16) unsigned short A_s[2][128 * 32];
  __shared__ __align__(16) unsigned short B_s[2][256 * 32];

  int dd = blockIdx.x;
  int b  = (dd & 7) + 8 * ((dd >> 3) >> 5);   // same XCD as K1/K2's batch b
  int mt = (dd >> 3) & 31;
  int n0 = mt << 7;
  const float* xb = x + ((size_t)b << 20);
  const unsigned short* ab = attnT + ((size_t)b << 16);
  float* ob = out + ((size_t)b << 20);

  int t = threadIdx.x, w = t >> 6, l = t & 63;
  int wm = w >> 1, wn = w & 1;
  int fr = l & 15, fh = l >> 4;

  int ar = t >> 1, ah = t & 1;             // A staging: row, half
  const float* aSrc = xb + (size_t)(n0 + ar) * 256 + ah * 16;
  int brow = l >> 2;                       // B staging: row in 16-row segment
  int bhi = (l & 3) ^ (brow & 3);          // pre-swizzled 16B slot

  f32x4 acc[4][8];
#pragma unroll
  for (int m = 0; m < 4; ++m)
#pragma unroll
    for (int n = 0; n < 8; ++n) acc[m][n] = (f32x4)(0.0f);

  auto STAGE_A = [&](int bsel, int k0) {
    uint32_t pk[8];
#pragma unroll
    for (int q = 0; q < 4; ++q) {
      fl4 v = *(const fl4*)&aSrc[k0 + q * 4];
      pk[2 * q]     = cvtpk(v.x, v.y);
      pk[2 * q + 1] = cvtpk(v.z, v.w);
    }
#pragma unroll
    for (int j = 0; j < 2; ++j) {
      int hi = ah * 2 + j;
      int byt = ar * 64 + ((hi ^ (ar & 3)) << 4);
      *(u32x4*)&A_s[bsel][byt >> 1] =
          u32x4{pk[4 * j], pk[4 * j + 1], pk[4 * j + 2], pk[4 * j + 3]};
    }
  };

  auto STAGE_B = [&](int bsel, int k0) {
#pragma unroll
    for (int r = 0; r < 4; ++r) {
      int seg = r * 4 + w;                 // 16 segments of 16 rows
      int row = seg * 16 + brow;
      gload16(&ab[(size_t)row * 256 + k0 + bhi * 8], &B_s[bsel][seg * 512]);
    }
  };

  STAGE_A(0, 0);
  STAGE_B(0, 0);
  __syncthreads();

  int buf = 0;
#pragma unroll 1
  for (int kt = 0; kt < 8; ++kt) {
    if (kt < 7) { STAGE_A(buf ^ 1, (kt + 1) * 32); STAGE_B(buf ^ 1, (kt + 1) * 32); }
    bf16x8s af[4];
#pragma unroll
    for (int m = 0; m < 4; ++m) {
      int row = wm * 64 + m * 16 + fr;
      int byt = row * 64 + ((fh ^ (row & 3)) << 4);
      af[m] = *(const bf16x8s*)&A_s[buf][byt >> 1];
    }
    bf16x8s bf[8];
#pragma unroll
    for (int n = 0; n < 8; ++n) {
      int dn = wn * 128 + n * 16 + fr;
      int byt = dn * 64 + ((fh ^ (dn & 3)) << 4);
      bf[n] = *(const bf16x8s*)&B_s[buf][byt >> 1];
    }
#pragma unroll
    for (int m = 0; m < 4; ++m)
#pragma unroll
      for (int n = 0; n < 8; ++n)
        acc[m][n] = __builtin_amdgcn_mfma_f32_16x16x32_bf16(
            af[m], bf[n], acc[m][n], 0, 0, 0);
    __syncthreads();
    buf ^= 1;
  }

  float g = gamma[0];
#pragma unroll
  for (int m = 0; m < 4; ++m) {
    int row = wm * 64 + m * 16 + fh * 4;
#pragma unroll
    for (int n = 0; n < 8; ++n) {
      int col = wn * 128 + n * 16 + fr;
#pragma unroll
      for (int i = 0; i < 4; ++i) {
        size_t idx = (size_t)(n0 + row + i) * 256 + col;
        ob[idx] = g * acc[m][n][i] + xb[idx];
      }
    }
  }
}

// ---------------------------------------------------------------- launch
extern "C" void kernel_launch(void* const* d_in, const int* in_sizes, int n_in,
                              void* d_out, int out_size, void* d_ws, size_t ws_size,
                              hipStream_t stream) {
  const float* x     = (const float*)d_in[0];
  const float* gamma = (const float*)d_in[1];
  float* out = (float*)d_out;

  // scratch layout: partials (64MB) live in d_out[64MB..128MB) (dead before K3
  // rewrites it; d_out is 134MB); attnT (4MB) in d_ws (K3 reads it while
  // writing d_out).
  float*          part  = (float*)((char*)d_out + (size_t)64 * 1024 * 1024);
  unsigned short* attnT = (unsigned short*)d_ws;

  k1_ata<<<1024, 256, 0, stream>>>(x, part);
  k2_softmax<<<128, 256, 0, stream>>>(part, attnT);
  k3_av<<<1024, 256, 0, stream>>>(x, attnT, gamma, out);
}

// Round 5
// 118.980 us; speedup vs baseline: 1.3887x; 1.3024x over previous
//
#include <hip/hip_runtime.h>
#include <hip/hip_bf16.h>
#include <stdint.h>

// CAM: out = gamma * (A @ softmax(A^T A)) + x,  A = x.reshape(B, N, C)
// B=32, N=4096 (64*64), C=256.
// Pipeline:
//   K1: full 256x256 symmetric aTa per (batch, K-slab) — one LDS tile is both
//       MFMA operands; x read exactly once. splitK=8. (partials d_out[64..128MB))
//   K2: reduce 8 partials + softmax + transpose -> attnT bf16 (d_ws, 4MB)
//   K3: out = gamma * (A @ attn) + x            (writes all of d_out)

typedef __attribute__((ext_vector_type(8))) short bf16x8s;
typedef __attribute__((ext_vector_type(8))) unsigned short u16x8;
typedef __attribute__((ext_vector_type(4))) float f32x4;
typedef __attribute__((ext_vector_type(4))) float fl4;
typedef __attribute__((ext_vector_type(4))) uint32_t u32x4;
typedef __attribute__((ext_vector_type(2))) uint32_t u32x2;

__device__ __forceinline__ unsigned short f2bf(float f) {
  union { float f; uint32_t u; } v; v.f = f;
  uint32_t r = v.u + 0x7FFFu + ((v.u >> 16) & 1u);
  return (unsigned short)(r >> 16);
}

// packed f32 pair -> 2x bf16 in one u32 (low = lo), RNE
__device__ __forceinline__ uint32_t cvtpk(float lo, float hi) {
  __hip_bfloat162 h = __float22bfloat162_rn(float2{lo, hi});
  union { __hip_bfloat162 h; uint32_t u; } v; v.h = h; return v.u;
}

__device__ __forceinline__ void gload16(const void* g, void* l) {
  __builtin_amdgcn_global_load_lds(
      (const __attribute__((address_space(1))) uint32_t*)g,
      (__attribute__((address_space(3))) uint32_t*)l, 16, 0, 0);
}

// ---------------------------------------------------------------- K1
// aTa[c,d] = sum_n x[n,c]*x[n,d] — symmetric, so stage ONE 256c x 64n bf16
// tile and use it as both A and B operands.  Per WG (512 thr, 8 waves):
// full 256x256 output, K-slab of 512 (splitK=8).  grid = 32*8 = 256.
// Each (b, ks) slab is read by exactly one WG -> x fetched once total.
// LDS: double-buffered [256 c][64 n] bf16, XOR-swizzled byte ^= (row&7)<<4.
// T14 staging: issue loads -> compute current tile -> cvt+ds_write -> barrier.
__global__ __launch_bounds__(512, 2) void k1_ata(
    const float* __restrict__ x, float* __restrict__ part) {
  __shared__ __align__(16) unsigned short S[2][256 * 64];

  int bid = blockIdx.x;                 // 0..255
  int b = bid >> 3, ks = bid & 7;
  const float* xb = x + ((size_t)b << 20);
  const int nsl = ks * 512;

  int t = threadIdx.x, w = t >> 6, l = t & 63;
  int wm = w >> 1, wn = w & 1;          // 4x2 wave grid: 64-row x 128-col
  int fr = l & 15, fh = l >> 4;

  int cb = (t >> 4) * 8;                // c-block 0..248
  int nb = (t & 15) * 4;                // n-quad 0..60

  f32x4 acc[4][8];
#pragma unroll
  for (int m = 0; m < 4; ++m)
#pragma unroll
    for (int n = 0; n < 8; ++n) acc[m][n] = (f32x4)(0.0f);

  fl4 lo[4], hi[4];                     // 4 n-rows x 8 c each, in flight
  auto LOAD = [&](int kt) {
    const float* s0 = xb + (size_t)(nsl + kt * 64 + nb) * 256 + cb;
#pragma unroll
    for (int r = 0; r < 4; ++r) {
      lo[r] = *(const fl4*)&s0[(size_t)r * 256];
      hi[r] = *(const fl4*)&s0[(size_t)r * 256 + 4];
    }
  };
  auto WRITE = [&](int bsel) {
#pragma unroll
    for (int i = 0; i < 8; ++i) {       // c-row cb+i; (cb+i)&7 == i
      float e0 = (i < 4) ? lo[0][i & 3] : hi[0][i & 3];
      float e1 = (i < 4) ? lo[1][i & 3] : hi[1][i & 3];
      float e2 = (i < 4) ? lo[2][i & 3] : hi[2][i & 3];
      float e3 = (i < 4) ? lo[3][i & 3] : hi[3][i & 3];
      uint32_t w0 = cvtpk(e0, e1), w1 = cvtpk(e2, e3);
      int byt = (cb + i) * 128 + ((nb * 2) ^ (i << 4));
      *(u32x2*)&S[bsel][byt >> 1] = u32x2{w0, w1};
    }
  };

  LOAD(0);
  WRITE(0);
  __syncthreads();

#pragma unroll 1
  for (int kt = 0; kt < 8; ++kt) {
    if (kt < 7) LOAD(kt + 1);
    const unsigned short* Sb = S[kt & 1];
#pragma unroll
    for (int h = 0; h < 2; ++h) {
      bf16x8s afr[4], bfr[8];
#pragma unroll
      for (int m = 0; m < 4; ++m) {
        int row = wm * 64 + m * 16 + fr;
        int byt = row * 128 + ((h * 64 + fh * 16) ^ ((row & 7) << 4));
        afr[m] = *(const bf16x8s*)&Sb[byt >> 1];
      }
#pragma unroll
      for (int n = 0; n < 8; ++n) {
        int row = wn * 128 + n * 16 + fr;
        int byt = row * 128 + ((h * 64 + fh * 16) ^ ((row & 7) << 4));
        bfr[n] = *(const bf16x8s*)&Sb[byt >> 1];
      }
#pragma unroll
      for (int m = 0; m < 4; ++m)
#pragma unroll
        for (int n = 0; n < 8; ++n)
          acc[m][n] = __builtin_amdgcn_mfma_f32_16x16x32_bf16(
              afr[m], bfr[n], acc[m][n], 0, 0, 0);
    }
    if (kt < 7) WRITE((kt + 1) & 1);
    __syncthreads();
  }

  float* pb = part + ((size_t)bid << 16);   // bid = b*8+ks, 256KB partial
#pragma unroll
  for (int m = 0; m < 4; ++m) {
    int row = wm * 64 + m * 16 + fh * 4;
#pragma unroll
    for (int n = 0; n < 8; ++n) {
      int col = wn * 128 + n * 16 + fr;
#pragma unroll
      for (int i = 0; i < 4; ++i)
        pb[(size_t)(row + i) * 256 + col] = acc[m][n][i];
    }
  }
}

// ---------------------------------------------------------------- K2
// sum 8 split-K partials, softmax over d, write attnT[b][d][c] (bf16).
// grid = 32*4 = 128 blocks (64 c-rows each), 256 threads (4 waves).
__global__ __launch_bounds__(256) void k2_softmax(
    const float* __restrict__ part, unsigned short* __restrict__ attnT) {
  __shared__ unsigned short T[256][66];
  int d = blockIdx.x;
  int b    = (d & 7) + 8 * ((d >> 3) >> 2);
  int cblk = (d >> 3) & 3;
  int t = threadIdx.x, w = t >> 6, l = t & 63;
  const float* pb = part + ((size_t)b * 8) * 65536 + (size_t)(cblk * 64) * 256;

  for (int it = 0; it < 16; ++it) {
    int c = w * 16 + it;                   // local row 0..63
    float s[4];
#pragma unroll
    for (int i = 0; i < 4; ++i) {
      int dd = l + 64 * i;
      float v = 0.0f;
#pragma unroll
      for (int k = 0; k < 8; ++k)
        v += pb[(size_t)k * 65536 + (size_t)c * 256 + dd];
      s[i] = v;
    }
    float mx = fmaxf(fmaxf(s[0], s[1]), fmaxf(s[2], s[3]));
    for (int off = 32; off; off >>= 1) mx = fmaxf(mx, __shfl_xor(mx, off));
    float sum = 0.0f;
#pragma unroll
    for (int i = 0; i < 4; ++i) { s[i] = __expf(s[i] - mx); sum += s[i]; }
    for (int off = 32; off; off >>= 1) sum += __shfl_xor(sum, off);
    float inv = 1.0f / sum;
#pragma unroll
    for (int i = 0; i < 4; ++i) T[l + 64 * i][c] = f2bf(s[i] * inv);
  }
  __syncthreads();

  unsigned short* ab = attnT + ((size_t)b << 16) + (size_t)t * 256 + cblk * 64;
#pragma unroll
  for (int c8 = 0; c8 < 8; ++c8) {
    u16x8 v;
#pragma unroll
    for (int j = 0; j < 8; ++j) v[j] = T[t][c8 * 8 + j];
    *(u16x8*)&ab[c8 * 8] = v;
  }
}

// ---------------------------------------------------------------- K3
// out[n,d] = gamma * sum_c x[n,c]*attn[c,d] + x[n,d].
// Per WG: 128n x 256d, K=256 in 8 steps of 32.  grid = 32*32 = 1024.
// A: reg-staged f32->bf16 (packed cvt) into swizzled LDS [128][32].
// B: global_load_lds from attnT into swizzled LDS [256][32].
__global__ __launch_bounds__(256, 2) void k3_av(
    const float* __restrict__ x, const unsigned short* __restrict__ attnT,
    const float* __restrict__ gamma, float* __restrict__ out) {
  __shared__ __align__(16) unsigned short A_s[2][128 * 32];
  __shared__ __align__(16) unsigned short B_s[2][256 * 32];

  int dd = blockIdx.x;
  int b  = (dd & 7) + 8 * ((dd >> 3) >> 5);   // XCD swizzle for L2 locality
  int mt = (dd >> 3) & 31;
  int n0 = mt << 7;
  const float* xb = x + ((size_t)b << 20);
  const unsigned short* ab = attnT + ((size_t)b << 16);
  float* ob = out + ((size_t)b << 20);

  int t = threadIdx.x, w = t >> 6, l = t & 63;
  int wm = w >> 1, wn = w & 1;
  int fr = l & 15, fh = l >> 4;

  int ar = t >> 1, ah = t & 1;             // A staging: row, half
  const float* aSrc = xb + (size_t)(n0 + ar) * 256 + ah * 16;
  int brow = l >> 2;                       // B staging: row in 16-row segment
  int bhi = (l & 3) ^ (brow & 3);          // pre-swizzled 16B slot

  f32x4 acc[4][8];
#pragma unroll
  for (int m = 0; m < 4; ++m)
#pragma unroll
    for (int n = 0; n < 8; ++n) acc[m][n] = (f32x4)(0.0f);

  auto STAGE_A = [&](int bsel, int k0) {
    uint32_t pk[8];
#pragma unroll
    for (int q = 0; q < 4; ++q) {
      fl4 v = *(const fl4*)&aSrc[k0 + q * 4];
      pk[2 * q]     = cvtpk(v.x, v.y);
      pk[2 * q + 1] = cvtpk(v.z, v.w);
    }
#pragma unroll
    for (int j = 0; j < 2; ++j) {
      int hi = ah * 2 + j;
      int byt = ar * 64 + ((hi ^ (ar & 3)) << 4);
      *(u32x4*)&A_s[bsel][byt >> 1] =
          u32x4{pk[4 * j], pk[4 * j + 1], pk[4 * j + 2], pk[4 * j + 3]};
    }
  };

  auto STAGE_B = [&](int bsel, int k0) {
#pragma unroll
    for (int r = 0; r < 4; ++r) {
      int seg = r * 4 + w;                 // 16 segments of 16 rows
      int row = seg * 16 + brow;
      gload16(&ab[(size_t)row * 256 + k0 + bhi * 8], &B_s[bsel][seg * 512]);
    }
  };

  STAGE_A(0, 0);
  STAGE_B(0, 0);
  __syncthreads();

  int buf = 0;
#pragma unroll 1
  for (int kt = 0; kt < 8; ++kt) {
    if (kt < 7) { STAGE_A(buf ^ 1, (kt + 1) * 32); STAGE_B(buf ^ 1, (kt + 1) * 32); }
    bf16x8s af[4];
#pragma unroll
    for (int m = 0; m < 4; ++m) {
      int row = wm * 64 + m * 16 + fr;
      int byt = row * 64 + ((fh ^ (row & 3)) << 4);
      af[m] = *(const bf16x8s*)&A_s[buf][byt >> 1];
    }
    bf16x8s bf[8];
#pragma unroll
    for (int n = 0; n < 8; ++n) {
      int dn = wn * 128 + n * 16 + fr;
      int byt = dn * 64 + ((fh ^ (dn & 3)) << 4);
      bf[n] = *(const bf16x8s*)&B_s[buf][byt >> 1];
    }
#pragma unroll
    for (int m = 0; m < 4; ++m)
#pragma unroll
      for (int n = 0; n < 8; ++n)
        acc[m][n] = __builtin_amdgcn_mfma_f32_16x16x32_bf16(
            af[m], bf[n], acc[m][n], 0, 0, 0);
    __syncthreads();
    buf ^= 1;
  }

  float g = gamma[0];
#pragma unroll
  for (int m = 0; m < 4; ++m) {
    int row = wm * 64 + m * 16 + fh * 4;
#pragma unroll
    for (int n = 0; n < 8; ++n) {
      int col = wn * 128 + n * 16 + fr;
#pragma unroll
      for (int i = 0; i < 4; ++i) {
        size_t idx = (size_t)(n0 + row + i) * 256 + col;
        ob[idx] = g * acc[m][n][i] + xb[idx];
      }
    }
  }
}

// ---------------------------------------------------------------- launch
extern "C" void kernel_launch(void* const* d_in, const int* in_sizes, int n_in,
                              void* d_out, int out_size, void* d_ws, size_t ws_size,
                              hipStream_t stream) {
  const float* x     = (const float*)d_in[0];
  const float* gamma = (const float*)d_in[1];
  float* out = (float*)d_out;

  // scratch layout: partials (64MB) live in d_out[64MB..128MB) (dead before K3
  // rewrites it); attnT (4MB) in d_ws (K3 reads it while writing d_out).
  float*          part  = (float*)((char*)d_out + (size_t)64 * 1024 * 1024);
  unsigned short* attnT = (unsigned short*)d_ws;

  k1_ata<<<256, 512, 0, stream>>>(x, part);
  k2_softmax<<<128, 256, 0, stream>>>(part, attnT);
  k3_av<<<1024, 256, 0, stream>>>(x, attnT, gamma, out);
}